// Round 19
// baseline (425.318 us; speedup 1.0000x reference)
//
#include <hip/hip_runtime.h>
#include <cstdio>

typedef unsigned short u16;
typedef u16 u16x4 __attribute__((ext_vector_type(4)));
typedef u16 u16x8 __attribute__((ext_vector_type(8)));
typedef __bf16 bf16x8 __attribute__((ext_vector_type(8)));
typedef float f32x4 __attribute__((ext_vector_type(4)));

#define AS1 __attribute__((address_space(1)))
#define AS3 __attribute__((address_space(3)))

#define GLOAD16(gsrc, ldst) __builtin_amdgcn_global_load_lds( \
    (const AS1 void*)(gsrc), (AS3 void*)(ldst), 16, 0, 0)

__device__ __forceinline__ u16 f2bf(float f) {
  unsigned u = __builtin_bit_cast(unsigned, f);
  u += 0x7fffu + ((u >> 16) & 1u);
  return (u16)(u >> 16);
}
__device__ __forceinline__ float bf2f(u16 h) {
  return __builtin_bit_cast(float, (unsigned)h << 16);
}

// ---------------- ALL fp32 -> bf16 conversions in one grid-stride kernel -----
// chunk ranges (8-elem units): hb[0,1048576) wA[..1605632) w2[..2195456)
// w4[..2457600) w5[..2981888). wA = q_a_w rows 0..1535 | kv_a_w rows
// 1536..2111 | zero rows 2112..2175.
__global__ __launch_bounds__(256) void cvt_all_k(
    const float* __restrict__ hidden, const float* __restrict__ q_a_w,
    const float* __restrict__ kv_a_w, const float* __restrict__ q_b_w,
    const float* __restrict__ kv_b_w, const float* __restrict__ o_w,
    u16* __restrict__ hb, u16* __restrict__ wA, u16* __restrict__ w2,
    u16* __restrict__ w4, u16* __restrict__ w5) {
  const long TOT = 2981888;
  for (long c = (long)blockIdx.x * 256 + threadIdx.x; c < TOT; c += (long)gridDim.x * 256) {
    const float* s = nullptr;
    u16* d;
    long e;
    if (c < 1048576)      { e = c * 8;               s = hidden + e;  d = hb + e; }
    else if (c < 1605632) { e = (c - 1048576) * 8;   d = wA + e;
                            const long row = e >> 11;
                            if (row < 1536)      s = q_a_w + e;
                            else if (row < 2112) s = kv_a_w + (e - 3145728); }
    else if (c < 2195456) { e = (c - 1605632) * 8;   s = q_b_w + e;   d = w2 + e; }
    else if (c < 2457600) { e = (c - 2195456) * 8;   s = kv_b_w + e;  d = w4 + e; }
    else                  { e = (c - 2457600) * 8;   s = o_w + e;     d = w5 + e; }
    u16x8 o = {0,0,0,0,0,0,0,0};
    if (s) {
      const float4* p = (const float4*)s;
      float4 a = p[0], b = p[1];
      o[0]=f2bf(a.x); o[1]=f2bf(a.y); o[2]=f2bf(a.z); o[3]=f2bf(a.w);
      o[4]=f2bf(b.x); o[5]=f2bf(b.y); o[6]=f2bf(b.z); o[7]=f2bf(b.w);
    }
    *(u16x8*)d = o;
  }
}

// ---------------- fused dual RMSNorm: q (1536 cols) + kv (512 cols) ----------
// waves 0..2 handle the q-norm (192 threads x 8), wave 3's 64 lanes cover the
// kv-norm exactly (in-wave reduction, no LDS).
__global__ __launch_bounds__(256) void rms2_k(const u16* __restrict__ qk_a,
                                              u16* __restrict__ qa, u16* __restrict__ ckv,
                                              const float* __restrict__ qw,
                                              const float* __restrict__ kw) {
  const int row = blockIdx.x;
  const int tid = threadIdx.x;
  const int w = tid >> 6;
  float x[8];
  float ss = 0.f;
  u16x8 v = *(const u16x8*)(qk_a + (size_t)row * 2176 + tid * 8);
#pragma unroll
  for (int j = 0; j < 8; ++j) { x[j] = bf2f(v[j]); ss += x[j] * x[j]; }
#pragma unroll
  for (int off = 1; off < 64; off <<= 1) ss += __shfl_xor(ss, off);
  __shared__ float red[3];
  if (w < 3 && (tid & 63) == 0) red[w] = ss;
  __syncthreads();
  if (w < 3) {
    const float tot = red[0] + red[1] + red[2];
    const float rs = 1.0f / sqrtf(tot / 1536.f + 1e-6f);
    u16x8 o;
#pragma unroll
    for (int j = 0; j < 8; ++j) o[j] = f2bf(x[j] * rs * qw[tid * 8 + j]);
    *(u16x8*)(qa + (size_t)row * 1536 + tid * 8) = o;
  } else {
    const float rs = 1.0f / sqrtf(ss / 512.f + 1e-6f);
    const int t = tid - 192;
    u16x8 o;
#pragma unroll
    for (int j = 0; j < 8; ++j) o[j] = f2bf(x[j] * rs * kw[t * 8 + j]);
    *(u16x8*)(ckv + (size_t)row * 512 + t * 8) = o;
  }
}

// ---------------- RoPE: q_pe (in place, 16 heads) + k_pe -> kpe --------------
__global__ __launch_bounds__(256) void rope_k(u16* __restrict__ q, const u16* __restrict__ qk_a,
                                              u16* __restrict__ kpe, const int* __restrict__ pos) {
  const int tok = blockIdx.x;          // 0..4095
  const int j = threadIdx.x & 63;
  const int w = threadIdx.x >> 6;
  const float p = (float)pos[tok];
  const int jj = j & 31;
  const float inv = __powf(10000.0f, -(float)jj * (1.0f / 32.0f));
  float s, c;
  __sincosf(p * inv, &s, &c);
  const float sgn = (j < 32) ? -1.0f : 1.0f;
  const int partner = (j < 32) ? j + 32 : j - 32;
  if (w == 0) {
    const float x  = bf2f(qk_a[(size_t)tok * 2176 + 2048 + j]);
    const float xp = bf2f(qk_a[(size_t)tok * 2176 + 2048 + partner]);
    kpe[(size_t)tok * 64 + j] = f2bf(x * c + sgn * xp * s);
  }
#pragma unroll
  for (int hh = 0; hh < 4; ++hh) {
    const int h = w * 4 + hh;
    const size_t base = (size_t)tok * 3072 + h * 192 + 128;
    const float x  = bf2f(q[base + j]);
    const float xp = bf2f(q[base + partner]);
    q[base + j] = f2bf(x * c + sgn * xp * s);
  }
}

// ---------------- bf16 GEMM 128x128 (m97 structure) + XCD swizzle (T1) -------
// cs: epilogue scale. vTr != nullptr => kv_b mode: cols 0..127 of each head's
// 256-col block -> Cb; cols 128..255 (V) written transposed to vTr packed u16x4.
__global__ __launch_bounds__(256) void gemm_bt(const u16* __restrict__ A, const u16* __restrict__ B,
                                               u16* __restrict__ Cb, float* __restrict__ Cf,
                                               int M, int N, int K, float cs,
                                               u16* __restrict__ vTr) {
  __shared__ __attribute__((aligned(16))) u16 As[128 * 64];
  __shared__ __attribute__((aligned(16))) u16 Bs[128 * 64];
  const int tid = threadIdx.x;
  // XCD-aware bijective remap (all grids have nwg % 8 == 0)
  const int nwg = gridDim.x * gridDim.y;
  const int lin = blockIdx.y * gridDim.x + blockIdx.x;
  const int swz = (lin & 7) * (nwg >> 3) + (lin >> 3);
  const int m0 = (swz / gridDim.x) * 128, n0 = (swz % gridDim.x) * 128;
  const int w = tid >> 6, lane = tid & 63;
  const int wr = w >> 1, wc = w & 1;
  const int lr = lane & 15, g = lane >> 4;

  f32x4 acc[4][4] = {};

  for (int k0 = 0; k0 < K; k0 += 64) {
#pragma unroll
    for (int i = 0; i < 4; ++i) {
      const int c = i * 256 + tid;
      const int row = c >> 3, col = (c & 7) << 3;
      GLOAD16(A + (size_t)(m0 + row) * K + k0 + col, &As[c * 8]);
    }
#pragma unroll
    for (int i = 0; i < 4; ++i) {
      const int c = i * 256 + tid;
      const int row = c >> 3, col = (c & 7) << 3;
      GLOAD16(B + (size_t)(n0 + row) * K + k0 + col, &Bs[c * 8]);
    }
    __syncthreads();
    bf16x8 af[4][2], bfr[4][2];
#pragma unroll
    for (int x = 0; x < 4; ++x)
#pragma unroll
      for (int kk = 0; kk < 2; ++kk) {
        af[x][kk]  = *(const bf16x8*)(&As[(wr * 64 + x * 16 + lr) * 64 + kk * 32 + g * 8]);
        bfr[x][kk] = *(const bf16x8*)(&Bs[(wc * 64 + x * 16 + lr) * 64 + kk * 32 + g * 8]);
      }
#pragma unroll
    for (int mi = 0; mi < 4; ++mi)
#pragma unroll
      for (int ni = 0; ni < 4; ++ni)
#pragma unroll
        for (int kk = 0; kk < 2; ++kk)
          acc[mi][ni] = __builtin_amdgcn_mfma_f32_16x16x32_bf16(af[mi][kk], bfr[ni][kk],
                                                                acc[mi][ni], 0, 0, 0);
    __syncthreads();
  }

  const int rb = m0 + wr * 64, cb = n0 + wc * 64;
#pragma unroll
  for (int mi = 0; mi < 4; ++mi)
#pragma unroll
    for (int ni = 0; ni < 4; ++ni) {
      const int r = rb + mi * 16 + g * 4;
      const int cI = cb + ni * 16 + lr;
      if (vTr) {
        const u16 v0 = f2bf(acc[mi][ni][0]), v1 = f2bf(acc[mi][ni][1]);
        const u16 v2 = f2bf(acc[mi][ni][2]), v3 = f2bf(acc[mi][ni][3]);
        if ((cI & 255) < 128) {               // k_nope -> kvb (row-major)
          Cb[(size_t)(r + 0) * N + cI] = v0;
          Cb[(size_t)(r + 1) * N + cI] = v1;
          Cb[(size_t)(r + 2) * N + cI] = v2;
          Cb[(size_t)(r + 3) * N + cI] = v3;
        } else {                              // V -> vT[bh*128+v][seq], packed
          u16x4 tq = {v0, v1, v2, v3};
          const int bh = ((r >> 11) << 4) + (cI >> 8);
          *(u16x4*)(vTr + (size_t)(bh * 128 + (cI & 127)) * 2048 + (r & 2047)) = tq;
        }
      } else {
#pragma unroll
        for (int i = 0; i < 4; ++i) {
          if (Cf) Cf[(size_t)(r + i) * N + cI] = acc[mi][ni][i] * cs;
          else    Cb[(size_t)(r + i) * N + cI] = f2bf(acc[mi][ni][i] * cs);
        }
      }
    }
}

// ---------------- causal flash attention, per (b,head) -----------------------
// r17/r18 template unchanged.
__global__ __launch_bounds__(256) void attn_k(const u16* __restrict__ q, const u16* __restrict__ kpe,
                                              const u16* __restrict__ vT, u16* __restrict__ ao) {
  __shared__ __attribute__((aligned(16))) u16 Ks[64 * 192];
  __shared__ __attribute__((aligned(16))) u16 Vt[128 * 64];
  __shared__ __attribute__((aligned(16))) u16 Ps[4][32 * 72];

  const int bh = blockIdx.x;
  const int b = bh >> 4, h = bh & 15;
  const int j = 15 - blockIdx.y;             // heavy q-tiles dispatch first (LPT)
  const int tid = threadIdx.x, w = tid >> 6, lane = tid & 63;
  const int lr = lane & 15, g = lane >> 4;

  const int q0 = j * 128;
  const int qrb = q0 + w * 32;
  u16* Psw = &Ps[w][0];

  int koff[6], kstep[6], kld[6];
#pragma unroll
  for (int i = 0; i < 6; ++i) {
    const int c = i * 256 + tid;             // 0..1535
    const int row = c / 24, cl = c - row * 24;
    const int cg = cl ^ (row & 7);
    kld[i] = c * 8;
    if (cg < 16) { koff[i] = 262144 + (b * 2048 + row) * 4096 + h * 256 + cg * 8;
                   kstep[i] = 64 * 4096; }
    else         { koff[i] = (b * 2048 + row) * 64 + (cg - 16) * 8;
                   kstep[i] = 64 * 64; }
  }
  int voff[4], vld[4];
#pragma unroll
  for (int i = 0; i < 4; ++i) {
    const int c = i * 256 + tid;             // 0..1023
    const int v = c >> 3, cl = c & 7;
    const int cg = cl ^ (v & 7);
    vld[i] = c * 8;
    voff[i] = (bh * 128 + v) * 2048 + cg * 8;
  }

  bf16x8 qf[2][6];
#pragma unroll
  for (int m = 0; m < 2; ++m)
#pragma unroll
    for (int kd = 0; kd < 6; ++kd)
      qf[m][kd] = *(const bf16x8*)(q + (size_t)(b * 2048 + qrb + m * 16 + lr) * 3072 +
                                   h * 192 + kd * 32 + g * 8);

  float mrow[2][4], lrow[2][4];
  f32x4 o[2][8] = {};
#pragma unroll
  for (int m = 0; m < 2; ++m)
#pragma unroll
    for (int i = 0; i < 4; ++i) { mrow[m][i] = -1e30f; lrow[m][i] = 0.f; }

  const int nt = (q0 >> 6) + 2;
  for (int t = 0; t < nt; ++t) {
    const int k0 = t * 64;
#pragma unroll
    for (int i = 0; i < 6; ++i) {
      GLOAD16(kpe + koff[i], &Ks[kld[i]]);
      koff[i] += kstep[i];
    }
#pragma unroll
    for (int i = 0; i < 4; ++i) {
      GLOAD16(vT + voff[i], &Vt[vld[i]]);
      voff[i] += 64;
    }
    __syncthreads();                         // publishes Ks/Vt for this tile

    const bool active = (k0 <= qrb + 31);    // wave-uniform
    if (active) {
      f32x4 sAcc[2][4] = {};
      __builtin_amdgcn_s_setprio(1);
#pragma unroll
      for (int nf = 0; nf < 4; ++nf) {
        const int rr = nf * 16 + lr;
#pragma unroll
        for (int kd = 0; kd < 6; ++kd) {
          const int ch = (kd * 4 + g) ^ (rr & 7);
          const bf16x8 kf = *(const bf16x8*)(&Ks[rr * 192 + ch * 8]);
#pragma unroll
          for (int m = 0; m < 2; ++m)
            sAcc[m][nf] = __builtin_amdgcn_mfma_f32_16x16x32_bf16(qf[m][kd], kf, sAcc[m][nf], 0, 0, 0);
        }
      }
      __builtin_amdgcn_s_setprio(0);

      const bool needMask = (k0 + 63 > qrb); // wave-uniform: diagonal tiles only
#pragma unroll
      for (int m = 0; m < 2; ++m) {
        float sv[4][4];
        if (needMask) {
#pragma unroll
          for (int nf = 0; nf < 4; ++nf)
#pragma unroll
            for (int i = 0; i < 4; ++i) {
              const int qrow = qrb + m * 16 + g * 4 + i;
              const int kcol = k0 + nf * 16 + lr;
              sv[nf][i] = (kcol > qrow) ? -1e30f : sAcc[m][nf][i];
            }
        } else {
#pragma unroll
          for (int nf = 0; nf < 4; ++nf)
#pragma unroll
            for (int i = 0; i < 4; ++i) sv[nf][i] = sAcc[m][nf][i];
        }
        float rm4[4];
        bool exceed = false;
#pragma unroll
        for (int i = 0; i < 4; ++i) {
          float rm = fmaxf(fmaxf(sv[0][i], sv[1][i]), fmaxf(sv[2][i], sv[3][i]));
          rm = fmaxf(rm, __shfl_xor(rm, 1));
          rm = fmaxf(rm, __shfl_xor(rm, 2));
          rm = fmaxf(rm, __shfl_xor(rm, 4));
          rm = fmaxf(rm, __shfl_xor(rm, 8));
          rm4[i] = rm;
          exceed = exceed || (rm > mrow[m][i] + 8.0f);
        }
        if (__any(exceed)) {                 // T13: rescale only on real max growth
#pragma unroll
          for (int i = 0; i < 4; ++i) {
            const float mn = fmaxf(mrow[m][i], rm4[i]);
            const float fac = __expf(mrow[m][i] - mn);
            mrow[m][i] = mn;
            lrow[m][i] *= fac;
#pragma unroll
            for (int nv = 0; nv < 8; ++nv) o[m][nv][i] *= fac;
          }
        }
#pragma unroll
        for (int i = 0; i < 4; ++i) {
          float rsum = 0.f;
#pragma unroll
          for (int nf = 0; nf < 4; ++nf) { sv[nf][i] = __expf(sv[nf][i] - mrow[m][i]); rsum += sv[nf][i]; }
          rsum += __shfl_xor(rsum, 1);
          rsum += __shfl_xor(rsum, 2);
          rsum += __shfl_xor(rsum, 4);
          rsum += __shfl_xor(rsum, 8);
          lrow[m][i] += rsum;
        }
#pragma unroll
        for (int nf = 0; nf < 4; ++nf)
#pragma unroll
          for (int i = 0; i < 4; ++i)
            Psw[(m * 16 + g * 4 + i) * 72 + nf * 16 + lr] = f2bf(sv[nf][i]);
      }
      asm volatile("s_waitcnt lgkmcnt(0)" ::: "memory");

      __builtin_amdgcn_s_setprio(1);
#pragma unroll
      for (int kc = 0; kc < 2; ++kc) {
        bf16x8 vfr[8];
#pragma unroll
        for (int nv = 0; nv < 8; ++nv) {
          const int v = nv * 16 + lr;
          const int cx = (kc * 4 + g) ^ (v & 7);
          vfr[nv] = *(const bf16x8*)(&Vt[v * 64 + cx * 8]);
        }
#pragma unroll
        for (int m = 0; m < 2; ++m) {
          const bf16x8 pf = *(const bf16x8*)(&Psw[(m * 16 + lr) * 72 + kc * 32 + g * 8]);
#pragma unroll
          for (int nv = 0; nv < 8; ++nv)
            o[m][nv] = __builtin_amdgcn_mfma_f32_16x16x32_bf16(pf, vfr[nv], o[m][nv], 0, 0, 0);
        }
      }
      __builtin_amdgcn_s_setprio(0);
    }
    __syncthreads();                         // Ks/Vt/Ps reads done before next stage
  }

#pragma unroll
  for (int m = 0; m < 2; ++m)
#pragma unroll
    for (int i = 0; i < 4; ++i) {
      const float inv = 1.0f / lrow[m][i];
      const size_t tokOff = (size_t)(b * 2048 + qrb + m * 16 + g * 4 + i) * 2048 + h * 128;
#pragma unroll
      for (int nv = 0; nv < 8; ++nv)
        ao[tokOff + nv * 16 + lr] = f2bf(o[m][nv][i] * inv);
    }
}

// -----------------------------------------------------------------------------
extern "C" void kernel_launch(void* const* d_in, const int* in_sizes, int n_in,
                              void* d_out, int out_size, void* d_ws, size_t ws_size,
                              hipStream_t stream) {
  const float* hidden  = (const float*)d_in[0];
  const int*   pos     = (const int*)d_in[1];
  const float* q_a_w   = (const float*)d_in[2];
  const float* q_a_ln  = (const float*)d_in[3];
  const float* q_b_w   = (const float*)d_in[4];
  const float* kv_a_w  = (const float*)d_in[5];
  const float* kv_a_ln = (const float*)d_in[6];
  const float* kv_b_w  = (const float*)d_in[7];
  const float* o_w     = (const float*)d_in[8];
  float* out = (float*)d_out;

  char* ws = (char*)d_ws;
  u16* hb  = (u16*)(ws + 0L);          // 4096x2048; reused as vT after fused a-GEMM
  u16* wA  = (u16*)(ws + 16777216L);   // 2176x2048
  u16* w2  = (u16*)(ws + 25690112L);   // 3072x1536
  u16* w4  = (u16*)(ws + 35127296L);   // 4096x512
  u16* w5  = (u16*)(ws + 39321600L);   // 2048x2048
  u16* qa  = (u16*)(ws + 47710208L);   // 4096x1536
  u16* qb  = (u16*)(ws + 60293120L);   // 4096x3072
  u16* ckv = (u16*)(ws + 85458944L);   // 4096x512
  u16* kpe = (u16*)(ws + 89653248L);   // 4096x64   (kvb = kpe + 262144 elements!)
  u16* kvb = (u16*)(ws + 90177536L);   // 4096x4096 (qk_a tmp aliases this region)
  u16* ao  = (u16*)(ws + 123731968L);  // 4096x2048
  u16* qk_a = kvb;                     // 4096x2176 fused a-GEMM output
  u16* vT  = hb;                       // 4096x2048
  if (ws_size < 145752064UL) { fprintf(stderr, "ws too small: %zu\n", ws_size); return; }

  const float SCALE = 0.07216878364870323f;  // 192^-0.5, folded into q_b GEMM

  cvt_all_k<<<dim3(2048), dim3(256), 0, stream>>>(hidden, q_a_w, kv_a_w, q_b_w, kv_b_w, o_w,
                                                  hb, wA, w2, w4, w5);
  // fused q_a + kv_a projection: qk_a[4096][2176]
  gemm_bt<<<dim3(17, 32), 256, 0, stream>>>(hb, wA, qk_a, nullptr, 4096, 2176, 2048, 1.0f, nullptr);
  rms2_k<<<4096, 256, 0, stream>>>(qk_a, qa, ckv, q_a_ln, kv_a_ln);
  gemm_bt<<<dim3(24, 32), 256, 0, stream>>>(qa, w2, qb, nullptr, 4096, 3072, 1536, SCALE, nullptr);
  rope_k<<<4096, 256, 0, stream>>>(qb, qk_a, kpe, pos);   // reads qk_a: before kvb overwrite
  // kv_b projection with fused V-transpose (k_nope -> kvb, V -> vT)
  gemm_bt<<<dim3(32, 32), 256, 0, stream>>>(ckv, w4, kvb, nullptr, 4096, 4096, 512, 1.0f, vT);
  attn_k<<<dim3(32, 16), 256, 0, stream>>>(qb, kpe, vT, ao);
  gemm_bt<<<dim3(16, 32), 256, 0, stream>>>(ao, w5, nullptr, out, 4096, 2048, 2048, 1.0f, nullptr);
}

// Round 20
// 405.981 us; speedup vs baseline: 1.0476x; 1.0476x over previous
//
#include <hip/hip_runtime.h>
#include <cstdio>

typedef unsigned short u16;
typedef u16 u16x4 __attribute__((ext_vector_type(4)));
typedef u16 u16x8 __attribute__((ext_vector_type(8)));
typedef __bf16 bf16x8 __attribute__((ext_vector_type(8)));
typedef float f32x4 __attribute__((ext_vector_type(4)));

#define AS1 __attribute__((address_space(1)))
#define AS3 __attribute__((address_space(3)))

#define GLOAD16(gsrc, ldst) __builtin_amdgcn_global_load_lds( \
    (const AS1 void*)(gsrc), (AS3 void*)(ldst), 16, 0, 0)

__device__ __forceinline__ u16 f2bf(float f) {
  unsigned u = __builtin_bit_cast(unsigned, f);
  u += 0x7fffu + ((u >> 16) & 1u);
  return (u16)(u >> 16);
}
__device__ __forceinline__ float bf2f(u16 h) {
  return __builtin_bit_cast(float, (unsigned)h << 16);
}

// ---------------- ALL fp32 -> bf16 conversions in one grid-stride kernel -----
__global__ __launch_bounds__(256) void cvt_all_k(
    const float* __restrict__ hidden, const float* __restrict__ q_a_w,
    const float* __restrict__ kv_a_w, const float* __restrict__ q_b_w,
    const float* __restrict__ kv_b_w, const float* __restrict__ o_w,
    u16* __restrict__ hb, u16* __restrict__ wA, u16* __restrict__ w2,
    u16* __restrict__ w4, u16* __restrict__ w5) {
  const long TOT = 2981888;
  for (long c = (long)blockIdx.x * 256 + threadIdx.x; c < TOT; c += (long)gridDim.x * 256) {
    const float* s = nullptr;
    u16* d;
    long e;
    if (c < 1048576)      { e = c * 8;               s = hidden + e;  d = hb + e; }
    else if (c < 1605632) { e = (c - 1048576) * 8;   d = wA + e;
                            const long row = e >> 11;
                            if (row < 1536)      s = q_a_w + e;
                            else if (row < 2112) s = kv_a_w + (e - 3145728); }
    else if (c < 2195456) { e = (c - 1605632) * 8;   s = q_b_w + e;   d = w2 + e; }
    else if (c < 2457600) { e = (c - 2195456) * 8;   s = kv_b_w + e;  d = w4 + e; }
    else                  { e = (c - 2457600) * 8;   s = o_w + e;     d = w5 + e; }
    u16x8 o = {0,0,0,0,0,0,0,0};
    if (s) {
      const float4* p = (const float4*)s;
      float4 a = p[0], b = p[1];
      o[0]=f2bf(a.x); o[1]=f2bf(a.y); o[2]=f2bf(a.z); o[3]=f2bf(a.w);
      o[4]=f2bf(b.x); o[5]=f2bf(b.y); o[6]=f2bf(b.z); o[7]=f2bf(b.w);
    }
    *(u16x8*)d = o;
  }
}

// ---------------- fused dual RMSNorm: q (1536 cols) + kv (512 cols) ----------
__global__ __launch_bounds__(256) void rms2_k(const u16* __restrict__ qk_a,
                                              u16* __restrict__ qa, u16* __restrict__ ckv,
                                              const float* __restrict__ qw,
                                              const float* __restrict__ kw) {
  const int row = blockIdx.x;
  const int tid = threadIdx.x;
  const int w = tid >> 6;
  float x[8];
  float ss = 0.f;
  u16x8 v = *(const u16x8*)(qk_a + (size_t)row * 2176 + tid * 8);
#pragma unroll
  for (int j = 0; j < 8; ++j) { x[j] = bf2f(v[j]); ss += x[j] * x[j]; }
#pragma unroll
  for (int off = 1; off < 64; off <<= 1) ss += __shfl_xor(ss, off);
  __shared__ float red[3];
  if (w < 3 && (tid & 63) == 0) red[w] = ss;
  __syncthreads();
  if (w < 3) {
    const float tot = red[0] + red[1] + red[2];
    const float rs = 1.0f / sqrtf(tot / 1536.f + 1e-6f);
    u16x8 o;
#pragma unroll
    for (int j = 0; j < 8; ++j) o[j] = f2bf(x[j] * rs * qw[tid * 8 + j]);
    *(u16x8*)(qa + (size_t)row * 1536 + tid * 8) = o;
  } else {
    const float rs = 1.0f / sqrtf(ss / 512.f + 1e-6f);
    const int t = tid - 192;
    u16x8 o;
#pragma unroll
    for (int j = 0; j < 8; ++j) o[j] = f2bf(x[j] * rs * kw[t * 8 + j]);
    *(u16x8*)(ckv + (size_t)row * 512 + t * 8) = o;
  }
}

// ---------------- RoPE: q_pe (in place, 16 heads) + k_pe -> kpe --------------
__global__ __launch_bounds__(256) void rope_k(u16* __restrict__ q, const u16* __restrict__ qk_a,
                                              u16* __restrict__ kpe, const int* __restrict__ pos) {
  const int tok = blockIdx.x;          // 0..4095
  const int j = threadIdx.x & 63;
  const int w = threadIdx.x >> 6;
  const float p = (float)pos[tok];
  const int jj = j & 31;
  const float inv = __powf(10000.0f, -(float)jj * (1.0f / 32.0f));
  float s, c;
  __sincosf(p * inv, &s, &c);
  const float sgn = (j < 32) ? -1.0f : 1.0f;
  const int partner = (j < 32) ? j + 32 : j - 32;
  if (w == 0) {
    const float x  = bf2f(qk_a[(size_t)tok * 2176 + 2048 + j]);
    const float xp = bf2f(qk_a[(size_t)tok * 2176 + 2048 + partner]);
    kpe[(size_t)tok * 64 + j] = f2bf(x * c + sgn * xp * s);
  }
#pragma unroll
  for (int hh = 0; hh < 4; ++hh) {
    const int h = w * 4 + hh;
    const size_t base = (size_t)tok * 3072 + h * 192 + 128;
    const float x  = bf2f(q[base + j]);
    const float xp = bf2f(q[base + partner]);
    q[base + j] = f2bf(x * c + sgn * xp * s);
  }
}

// ---------------- bf16 GEMM 128x128 (m97 structure, r18 mapping) -------------
__global__ __launch_bounds__(256) void gemm_bt(const u16* __restrict__ A, const u16* __restrict__ B,
                                               u16* __restrict__ Cb, float* __restrict__ Cf,
                                               int M, int N, int K, float cs,
                                               u16* __restrict__ vTr) {
  __shared__ __attribute__((aligned(16))) u16 As[128 * 64];
  __shared__ __attribute__((aligned(16))) u16 Bs[128 * 64];
  const int tid = threadIdx.x;
  const int m0 = blockIdx.y * 128, n0 = blockIdx.x * 128;
  const int w = tid >> 6, lane = tid & 63;
  const int wr = w >> 1, wc = w & 1;
  const int lr = lane & 15, g = lane >> 4;

  f32x4 acc[4][4] = {};

  for (int k0 = 0; k0 < K; k0 += 64) {
#pragma unroll
    for (int i = 0; i < 4; ++i) {
      const int c = i * 256 + tid;
      const int row = c >> 3, col = (c & 7) << 3;
      GLOAD16(A + (size_t)(m0 + row) * K + k0 + col, &As[c * 8]);
    }
#pragma unroll
    for (int i = 0; i < 4; ++i) {
      const int c = i * 256 + tid;
      const int row = c >> 3, col = (c & 7) << 3;
      GLOAD16(B + (size_t)(n0 + row) * K + k0 + col, &Bs[c * 8]);
    }
    __syncthreads();
    bf16x8 af[4][2], bfr[4][2];
#pragma unroll
    for (int x = 0; x < 4; ++x)
#pragma unroll
      for (int kk = 0; kk < 2; ++kk) {
        af[x][kk]  = *(const bf16x8*)(&As[(wr * 64 + x * 16 + lr) * 64 + kk * 32 + g * 8]);
        bfr[x][kk] = *(const bf16x8*)(&Bs[(wc * 64 + x * 16 + lr) * 64 + kk * 32 + g * 8]);
      }
#pragma unroll
    for (int mi = 0; mi < 4; ++mi)
#pragma unroll
      for (int ni = 0; ni < 4; ++ni)
#pragma unroll
        for (int kk = 0; kk < 2; ++kk)
          acc[mi][ni] = __builtin_amdgcn_mfma_f32_16x16x32_bf16(af[mi][kk], bfr[ni][kk],
                                                                acc[mi][ni], 0, 0, 0);
    __syncthreads();
  }

  const int rb = m0 + wr * 64, cb = n0 + wc * 64;
#pragma unroll
  for (int mi = 0; mi < 4; ++mi)
#pragma unroll
    for (int ni = 0; ni < 4; ++ni) {
      const int r = rb + mi * 16 + g * 4;
      const int cI = cb + ni * 16 + lr;
      if (vTr) {
        const u16 v0 = f2bf(acc[mi][ni][0]), v1 = f2bf(acc[mi][ni][1]);
        const u16 v2 = f2bf(acc[mi][ni][2]), v3 = f2bf(acc[mi][ni][3]);
        if ((cI & 255) < 128) {               // k_nope -> kvb (row-major)
          Cb[(size_t)(r + 0) * N + cI] = v0;
          Cb[(size_t)(r + 1) * N + cI] = v1;
          Cb[(size_t)(r + 2) * N + cI] = v2;
          Cb[(size_t)(r + 3) * N + cI] = v3;
        } else {                              // V -> vT[bh*128+v][seq], packed
          u16x4 tq = {v0, v1, v2, v3};
          const int bh = ((r >> 11) << 4) + (cI >> 8);
          *(u16x4*)(vTr + (size_t)(bh * 128 + (cI & 127)) * 2048 + (r & 2047)) = tq;
        }
      } else {
#pragma unroll
        for (int i = 0; i < 4; ++i) {
          if (Cf) Cf[(size_t)(r + i) * N + cI] = acc[mi][ni][i] * cs;
          else    Cb[(size_t)(r + i) * N + cI] = f2bf(acc[mi][ni][i] * cs);
        }
      }
    }
}

// ---------------- causal flash attention, per (b,head) -----------------------
// r18 template + deferred l-reduction: lrow is a PER-LANE partial (each lane
// sums its own 4 kcols); the 16-lane row reduce happens ONCE in the epilogue
// instead of 32 shuffles per tile. Rescale multiplies partials uniformly.
__global__ __launch_bounds__(256) void attn_k(const u16* __restrict__ q, const u16* __restrict__ kpe,
                                              const u16* __restrict__ vT, u16* __restrict__ ao) {
  __shared__ __attribute__((aligned(16))) u16 Ks[64 * 192];
  __shared__ __attribute__((aligned(16))) u16 Vt[128 * 64];
  __shared__ __attribute__((aligned(16))) u16 Ps[4][32 * 72];

  const int bh = blockIdx.x;
  const int b = bh >> 4, h = bh & 15;
  const int j = 15 - blockIdx.y;             // heavy q-tiles dispatch first (LPT)
  const int tid = threadIdx.x, w = tid >> 6, lane = tid & 63;
  const int lr = lane & 15, g = lane >> 4;

  const int q0 = j * 128;
  const int qrb = q0 + w * 32;
  u16* Psw = &Ps[w][0];

  int koff[6], kstep[6], kld[6];
#pragma unroll
  for (int i = 0; i < 6; ++i) {
    const int c = i * 256 + tid;             // 0..1535
    const int row = c / 24, cl = c - row * 24;
    const int cg = cl ^ (row & 7);
    kld[i] = c * 8;
    if (cg < 16) { koff[i] = 262144 + (b * 2048 + row) * 4096 + h * 256 + cg * 8;
                   kstep[i] = 64 * 4096; }
    else         { koff[i] = (b * 2048 + row) * 64 + (cg - 16) * 8;
                   kstep[i] = 64 * 64; }
  }
  int voff[4], vld[4];
#pragma unroll
  for (int i = 0; i < 4; ++i) {
    const int c = i * 256 + tid;             // 0..1023
    const int v = c >> 3, cl = c & 7;
    const int cg = cl ^ (v & 7);
    vld[i] = c * 8;
    voff[i] = (bh * 128 + v) * 2048 + cg * 8;
  }

  bf16x8 qf[2][6];
#pragma unroll
  for (int m = 0; m < 2; ++m)
#pragma unroll
    for (int kd = 0; kd < 6; ++kd)
      qf[m][kd] = *(const bf16x8*)(q + (size_t)(b * 2048 + qrb + m * 16 + lr) * 3072 +
                                   h * 192 + kd * 32 + g * 8);

  float mrow[2][4], lrow[2][4];              // lrow = per-lane partial sums
  f32x4 o[2][8] = {};
#pragma unroll
  for (int m = 0; m < 2; ++m)
#pragma unroll
    for (int i = 0; i < 4; ++i) { mrow[m][i] = -1e30f; lrow[m][i] = 0.f; }

  const int nt = (q0 >> 6) + 2;
  for (int t = 0; t < nt; ++t) {
    const int k0 = t * 64;
#pragma unroll
    for (int i = 0; i < 6; ++i) {
      GLOAD16(kpe + koff[i], &Ks[kld[i]]);
      koff[i] += kstep[i];
    }
#pragma unroll
    for (int i = 0; i < 4; ++i) {
      GLOAD16(vT + voff[i], &Vt[vld[i]]);
      voff[i] += 64;
    }
    __syncthreads();                         // publishes Ks/Vt for this tile

    const bool active = (k0 <= qrb + 31);    // wave-uniform
    if (active) {
      f32x4 sAcc[2][4] = {};
      __builtin_amdgcn_s_setprio(1);
#pragma unroll
      for (int nf = 0; nf < 4; ++nf) {
        const int rr = nf * 16 + lr;
#pragma unroll
        for (int kd = 0; kd < 6; ++kd) {
          const int ch = (kd * 4 + g) ^ (rr & 7);
          const bf16x8 kf = *(const bf16x8*)(&Ks[rr * 192 + ch * 8]);
#pragma unroll
          for (int m = 0; m < 2; ++m)
            sAcc[m][nf] = __builtin_amdgcn_mfma_f32_16x16x32_bf16(qf[m][kd], kf, sAcc[m][nf], 0, 0, 0);
        }
      }
      __builtin_amdgcn_s_setprio(0);

      const bool needMask = (k0 + 63 > qrb); // wave-uniform: diagonal tiles only
#pragma unroll
      for (int m = 0; m < 2; ++m) {
        float sv[4][4];
        if (needMask) {
#pragma unroll
          for (int nf = 0; nf < 4; ++nf)
#pragma unroll
            for (int i = 0; i < 4; ++i) {
              const int qrow = qrb + m * 16 + g * 4 + i;
              const int kcol = k0 + nf * 16 + lr;
              sv[nf][i] = (kcol > qrow) ? -1e30f : sAcc[m][nf][i];
            }
        } else {
#pragma unroll
          for (int nf = 0; nf < 4; ++nf)
#pragma unroll
            for (int i = 0; i < 4; ++i) sv[nf][i] = sAcc[m][nf][i];
        }
        float rm4[4];
        bool exceed = false;
#pragma unroll
        for (int i = 0; i < 4; ++i) {
          float rm = fmaxf(fmaxf(sv[0][i], sv[1][i]), fmaxf(sv[2][i], sv[3][i]));
          rm = fmaxf(rm, __shfl_xor(rm, 1));
          rm = fmaxf(rm, __shfl_xor(rm, 2));
          rm = fmaxf(rm, __shfl_xor(rm, 4));
          rm = fmaxf(rm, __shfl_xor(rm, 8));
          rm4[i] = rm;
          exceed = exceed || (rm > mrow[m][i] + 8.0f);
        }
        if (__any(exceed)) {                 // T13: rescale only on real max growth
#pragma unroll
          for (int i = 0; i < 4; ++i) {
            const float mn = fmaxf(mrow[m][i], rm4[i]);
            const float fac = __expf(mrow[m][i] - mn);
            mrow[m][i] = mn;
            lrow[m][i] *= fac;
#pragma unroll
            for (int nv = 0; nv < 8; ++nv) o[m][nv][i] *= fac;
          }
        }
#pragma unroll
        for (int i = 0; i < 4; ++i) {
          float rsum = 0.f;
#pragma unroll
          for (int nf = 0; nf < 4; ++nf) { sv[nf][i] = __expf(sv[nf][i] - mrow[m][i]); rsum += sv[nf][i]; }
          lrow[m][i] += rsum;                // per-lane partial; reduce in epilogue
        }
#pragma unroll
        for (int nf = 0; nf < 4; ++nf)
#pragma unroll
          for (int i = 0; i < 4; ++i)
            Psw[(m * 16 + g * 4 + i) * 72 + nf * 16 + lr] = f2bf(sv[nf][i]);
      }
      asm volatile("s_waitcnt lgkmcnt(0)" ::: "memory");

      __builtin_amdgcn_s_setprio(1);
#pragma unroll
      for (int kc = 0; kc < 2; ++kc) {
        bf16x8 vfr[8];
#pragma unroll
        for (int nv = 0; nv < 8; ++nv) {
          const int v = nv * 16 + lr;
          const int cx = (kc * 4 + g) ^ (v & 7);
          vfr[nv] = *(const bf16x8*)(&Vt[v * 64 + cx * 8]);
        }
#pragma unroll
        for (int m = 0; m < 2; ++m) {
          const bf16x8 pf = *(const bf16x8*)(&Psw[(m * 16 + lr) * 72 + kc * 32 + g * 8]);
#pragma unroll
          for (int nv = 0; nv < 8; ++nv)
            o[m][nv] = __builtin_amdgcn_mfma_f32_16x16x32_bf16(pf, vfr[nv], o[m][nv], 0, 0, 0);
        }
      }
      __builtin_amdgcn_s_setprio(0);
    }
    __syncthreads();                         // Ks/Vt/Ps reads done before next stage
  }

  // epilogue: final l reduce (once) + normalize and store
#pragma unroll
  for (int m = 0; m < 2; ++m)
#pragma unroll
    for (int i = 0; i < 4; ++i) {
      float ls = lrow[m][i];
      ls += __shfl_xor(ls, 1);
      ls += __shfl_xor(ls, 2);
      ls += __shfl_xor(ls, 4);
      ls += __shfl_xor(ls, 8);
      const float inv = 1.0f / ls;
      const size_t tokOff = (size_t)(b * 2048 + qrb + m * 16 + g * 4 + i) * 2048 + h * 128;
#pragma unroll
      for (int nv = 0; nv < 8; ++nv)
        ao[tokOff + nv * 16 + lr] = f2bf(o[m][nv][i] * inv);
    }
}

// -----------------------------------------------------------------------------
extern "C" void kernel_launch(void* const* d_in, const int* in_sizes, int n_in,
                              void* d_out, int out_size, void* d_ws, size_t ws_size,
                              hipStream_t stream) {
  const float* hidden  = (const float*)d_in[0];
  const int*   pos     = (const int*)d_in[1];
  const float* q_a_w   = (const float*)d_in[2];
  const float* q_a_ln  = (const float*)d_in[3];
  const float* q_b_w   = (const float*)d_in[4];
  const float* kv_a_w  = (const float*)d_in[5];
  const float* kv_a_ln = (const float*)d_in[6];
  const float* kv_b_w  = (const float*)d_in[7];
  const float* o_w     = (const float*)d_in[8];
  float* out = (float*)d_out;

  char* ws = (char*)d_ws;
  u16* hb  = (u16*)(ws + 0L);          // 4096x2048; reused as vT after fused a-GEMM
  u16* wA  = (u16*)(ws + 16777216L);   // 2176x2048
  u16* w2  = (u16*)(ws + 25690112L);   // 3072x1536
  u16* w4  = (u16*)(ws + 35127296L);   // 4096x512
  u16* w5  = (u16*)(ws + 39321600L);   // 2048x2048
  u16* qa  = (u16*)(ws + 47710208L);   // 4096x1536
  u16* qb  = (u16*)(ws + 60293120L);   // 4096x3072
  u16* ckv = (u16*)(ws + 85458944L);   // 4096x512
  u16* kpe = (u16*)(ws + 89653248L);   // 4096x64   (kvb = kpe + 262144 elements!)
  u16* kvb = (u16*)(ws + 90177536L);   // 4096x4096 (qk_a tmp aliases this region)
  u16* ao  = (u16*)(ws + 123731968L);  // 4096x2048
  u16* qk_a = kvb;                     // 4096x2176 fused a-GEMM output
  u16* vT  = hb;                       // 4096x2048
  if (ws_size < 145752064UL) { fprintf(stderr, "ws too small: %zu\n", ws_size); return; }

  const float SCALE = 0.07216878364870323f;  // 192^-0.5, folded into q_b GEMM

  cvt_all_k<<<dim3(2048), dim3(256), 0, stream>>>(hidden, q_a_w, kv_a_w, q_b_w, kv_b_w, o_w,
                                                  hb, wA, w2, w4, w5);
  // fused q_a + kv_a projection: qk_a[4096][2176]
  gemm_bt<<<dim3(17, 32), 256, 0, stream>>>(hb, wA, qk_a, nullptr, 4096, 2176, 2048, 1.0f, nullptr);
  rms2_k<<<4096, 256, 0, stream>>>(qk_a, qa, ckv, q_a_ln, kv_a_ln);
  gemm_bt<<<dim3(24, 32), 256, 0, stream>>>(qa, w2, qb, nullptr, 4096, 3072, 1536, SCALE, nullptr);
  rope_k<<<4096, 256, 0, stream>>>(qb, qk_a, kpe, pos);   // reads qk_a: before kvb overwrite
  // kv_b projection with fused V-transpose (k_nope -> kvb, V -> vT)
  gemm_bt<<<dim3(32, 32), 256, 0, stream>>>(ckv, w4, kvb, nullptr, 4096, 4096, 512, 1.0f, vT);
  attn_k<<<dim3(32, 16), 256, 0, stream>>>(qb, kpe, vT, ao);
  gemm_bt<<<dim3(16, 32), 256, 0, stream>>>(ao, w5, nullptr, out, 4096, 2048, 2048, 1.0f, nullptr);
}